// Round 1
// baseline (795.677 us; speedup 1.0000x reference)
//
#include <hip/hip_runtime.h>
#include <math.h>

#define GRID 64
#define CELLPX 16
#define CH 40
#define IMW 1024

__device__ __forceinline__ float gelu_tanh(float x) {
    float x3 = x * x * x;
    float t = tanhf(0.7978845608028654f * (x + 0.044715f * x3));
    return 0.5f * x * (1.0f + t);
}

__global__ __launch_bounds__(256) void sgn_kernel(
    const float* __restrict__ img,
    const float* __restrict__ w1, const float* __restrict__ b1,
    const float* __restrict__ s1, const float* __restrict__ bb1,
    const float* __restrict__ w2, const float* __restrict__ b2,
    const float* __restrict__ s2, const float* __restrict__ bb2,
    const float* __restrict__ dw, const float* __restrict__ db,
    float* __restrict__ out)
{
    __shared__ float img_s[16][16];
    __shared__ float x1s[256 * CH];   // conv1 output (LN+gelu), channel-rotated per position
    __shared__ float y2s[64 * 41];    // conv2 raw, then LN2+gelu in place (stride 41 vs banks)
    __shared__ float z1s[CH];         // constant vector for zero-input positions
    __shared__ float red[4][6];

    const int f   = blockIdx.x;
    const int cfg = f >> 10;
    const int ij  = f & 1023;
    const int ti  = ij >> 5, tj = ij & 31;
    const int sx  = cfg & 1, sy = cfg >> 1;   // order (0,0),(1,0),(0,1),(1,1)
    const int cr  = 2 * ti + sx, cc = 2 * tj + sy;

    const int t = threadIdx.x;

    // ---- stage the 16x16 image cell ----
    {
        int r = t >> 4, c = t & 15;
        img_s[r][c] = img[(cr * CELLPX + r) * IMW + cc * CELLPX + c];
    }
    // ---- z1 = gelu(LN(conv1_b)) (constant for all-zero-input positions) ----
    if (t < CH) {
        float mu = 0.f, m2 = 0.f;
        for (int i = 0; i < CH; i++) { float v = b1[i]; mu += v; }
        mu /= CH;
        for (int i = 0; i < CH; i++) { float d = b1[i] - mu; m2 += d * d; }
        float var = m2 / CH;
        float y = (b1[t] - mu) * rsqrtf(var + 1e-6f) * s1[t] + bb1[t];
        z1s[t] = gelu_tanh(y);
    }
    __syncthreads();

    // ---- conv1 (3x3 s2 SAME on 32x32 token, nonzero only top-left 16x16) + LN + gelu ----
    {
        int p = t >> 4, q = t & 15;
        int rot = (t >> 2) & 31;   // channel rotation to spread LDS banks
        if (p < 8 && q < 8) {
            float vin[9];
            #pragma unroll
            for (int dr = 0; dr < 3; dr++)
                #pragma unroll
                for (int dc = 0; dc < 3; dc++) {
                    int r = 2 * p + dr, c = 2 * q + dc;
                    vin[dr * 3 + dc] = (r < 16 && c < 16) ? img_s[r][c] : 0.0f;
                }
            float y[CH];
            float mu = 0.f;
            for (int ch = 0; ch < CH; ch++) {
                float a = b1[ch];
                #pragma unroll
                for (int k = 0; k < 9; k++) a += vin[k] * w1[k * CH + ch];
                y[ch] = a; mu += a;
            }
            mu /= CH;
            float var = 0.f;
            for (int ch = 0; ch < CH; ch++) { float d = y[ch] - mu; var += d * d; }
            var /= CH;
            float rs = rsqrtf(var + 1e-6f);
            for (int ch = 0; ch < CH; ch++) {
                float v = gelu_tanh((y[ch] - mu) * rs * s1[ch] + bb1[ch]);
                int slot = ch + rot; if (slot >= CH) slot -= CH;
                x1s[t * CH + slot] = v;
            }
        } else {
            for (int ch = 0; ch < CH; ch++) {
                int slot = ch + rot; if (slot >= CH) slot -= CH;
                x1s[t * CH + slot] = z1s[ch];
            }
        }
    }
    __syncthreads();

    // ---- conv2 (3x3 s2 SAME on 16x16x40 -> 8x8x40) ----
    {
        int pos = t & 63, grp = t >> 6;
        int p = pos >> 3, q = pos & 7;
        int co0 = grp * 10;
        float acc[10];
        #pragma unroll
        for (int u = 0; u < 10; u++) acc[u] = b2[co0 + u];
        for (int dr = 0; dr < 3; dr++) {
            int r = 2 * p + dr; if (r >= 16) continue;
            for (int dc = 0; dc < 3; dc++) {
                int c = 2 * q + dc; if (c >= 16) continue;
                int pos2 = r * 16 + c;
                int rot2 = (pos2 >> 2) & 31;
                const float* wrow = &w2[((dr * 3 + dc) * CH) * CH + co0];
                int slot = rot2;                 // slot for ci=0
                const float* xrow = &x1s[pos2 * CH];
                for (int ci = 0; ci < CH; ci++) {
                    float v = xrow[slot];
                    slot++; if (slot >= CH) slot -= CH;
                    const float* wp = wrow + ci * CH;
                    #pragma unroll
                    for (int u = 0; u < 10; u++) acc[u] += v * wp[u];
                }
            }
        }
        #pragma unroll
        for (int u = 0; u < 10; u++) y2s[pos * 41 + co0 + u] = acc[u];
    }
    __syncthreads();

    // ---- LN2 + gelu (in place) ----
    if (t < 64) {
        float mu = 0.f;
        for (int ch = 0; ch < CH; ch++) mu += y2s[t * 41 + ch];
        mu /= CH;
        float var = 0.f;
        for (int ch = 0; ch < CH; ch++) { float d = y2s[t * 41 + ch] - mu; var += d * d; }
        var /= CH;
        float rs = rsqrtf(var + 1e-6f);
        for (int ch = 0; ch < CH; ch++) {
            float v = y2s[t * 41 + ch];
            y2s[t * 41 + ch] = gelu_tanh((v - mu) * rs * s2[ch] + bb2[ch]);
        }
    }
    __syncthreads();

    // ---- dense: [2560] @ [2560,6] + b ----
    {
        float acc[6] = {0.f, 0.f, 0.f, 0.f, 0.f, 0.f};
        int i0 = t * 10;
        for (int ii = 0; ii < 10; ii++) {
            int i = i0 + ii;
            int pos = i / CH, ch = i - pos * CH;
            float v = y2s[pos * 41 + ch];
            const float* wp = &dw[i * 6];
            #pragma unroll
            for (int k = 0; k < 6; k++) acc[k] += v * wp[k];
        }
        #pragma unroll
        for (int off = 32; off > 0; off >>= 1)
            #pragma unroll
            for (int k = 0; k < 6; k++) acc[k] += __shfl_down(acc[k], off, 64);
        int wv = t >> 6, lane = t & 63;
        if (lane == 0) {
            #pragma unroll
            for (int k = 0; k < 6; k++) red[wv][k] = acc[k];
        }
        __syncthreads();
        if (t == 0) {
            #pragma unroll
            for (int k = 0; k < 6; k++) {
                float s = red[0][k] + red[1][k] + red[2][k] + red[3][k] + db[k];
                out[f * 6 + k] = s;
            }
        }
    }
}

extern "C" void kernel_launch(void* const* d_in, const int* in_sizes, int n_in,
                              void* d_out, int out_size, void* d_ws, size_t ws_size,
                              hipStream_t stream) {
    const float* img = (const float*)d_in[0];
    // d_in[1] = masks: analytically redundant (mask == cell id), not read.
    const float* w1  = (const float*)d_in[2];
    const float* b1  = (const float*)d_in[3];
    const float* s1  = (const float*)d_in[4];
    const float* bb1 = (const float*)d_in[5];
    const float* w2  = (const float*)d_in[6];
    const float* b2  = (const float*)d_in[7];
    const float* s2  = (const float*)d_in[8];
    const float* bb2 = (const float*)d_in[9];
    const float* dw  = (const float*)d_in[10];
    const float* db  = (const float*)d_in[11];
    float* out = (float*)d_out;

    sgn_kernel<<<4096, 256, 0, stream>>>(img, w1, b1, s1, bb1,
                                         w2, b2, s2, bb2, dw, db, out);
}

// Round 2
// 112.778 us; speedup vs baseline: 7.0552x; 7.0552x over previous
//
#include <hip/hip_runtime.h>
#include <math.h>

#define CH 40
#define IMW 1024
#define XS 48                 // halves per x1 position (padded from 40)
#define W2T_HALVES (48*48*8)  // [kchunk 0..47][co 0..47][j 0..7]
#define Z1_OFF W2T_HALVES     // z1[40] halves right after w2t

typedef _Float16 v8h __attribute__((ext_vector_type(8)));
typedef float    v4f __attribute__((ext_vector_type(4)));

__device__ __forceinline__ float gelu_tanh(float x) {
    float x3 = x * x * x;
    float t = tanhf(0.7978845608028654f * (x + 0.044715f * x3));
    return 0.5f * x * (1.0f + t);
}

// ---------------- pre-kernel: build f16 weight table + z1 in ws ----------------
__global__ __launch_bounds__(256) void prep_kernel(
    const float* __restrict__ w2,
    const float* __restrict__ b1, const float* __restrict__ s1,
    const float* __restrict__ bb1,
    _Float16* __restrict__ ws)
{
    int t = threadIdx.x;
    for (int idx = t; idx < W2T_HALVES; idx += 256) {
        int j   = idx & 7;
        int co  = (idx >> 3) % 48;
        int kgg = idx / (48 * 8);
        int k   = kgg * 8 + j;          // k = window*40 + ci
        float v = 0.0f;
        if (co < CH && k < 360) {
            int wi = k / 40, ci = k - wi * 40;
            v = w2[(wi * CH + ci) * CH + co];
        }
        ws[idx] = (_Float16)v;
    }
    if (t < CH) {
        float mu = 0.f, m2 = 0.f;
        for (int i = 0; i < CH; i++) mu += b1[i];
        mu /= CH;
        for (int i = 0; i < CH; i++) { float d = b1[i] - mu; m2 += d * d; }
        float rs = rsqrtf(m2 / CH + 1e-6f);
        float y = (b1[t] - mu) * rs * s1[t] + bb1[t];
        ws[Z1_OFF + t] = (_Float16)gelu_tanh(y);
    }
}

// ---------------- main kernel: one token per block ----------------
__global__ __launch_bounds__(256) void sgn_kernel(
    const float* __restrict__ img,
    const float* __restrict__ w1, const float* __restrict__ b1,
    const float* __restrict__ s1, const float* __restrict__ bb1,
    const float* __restrict__ b2g,
    const float* __restrict__ s2, const float* __restrict__ bb2,
    const float* __restrict__ dw, const float* __restrict__ db,
    const _Float16* __restrict__ ws,
    float* __restrict__ out)
{
    __shared__ float img_s[16][16];
    __shared__ __align__(16) _Float16 x1h[17 * 17 * XS];  // [r][c][ch] zero-padded border
    __shared__ unsigned koff_s[48];                       // per (step, kgroup) A-offset
    __shared__ float y2s[64 * 41];
    __shared__ float red[4][6];

    const int f   = blockIdx.x;
    const int cfg = f >> 10;
    const int ij  = f & 1023;
    const int ti  = ij >> 5, tj = ij & 31;
    const int sx  = cfg & 1, sy = cfg >> 1;
    const int cr  = 2 * ti + sx, cc = 2 * tj + sy;

    const int t = threadIdx.x;

    // ---- Phase A: stage image cell + build koff LUT ----
    {
        int r = t >> 4, c = t & 15;
        img_s[r][c] = img[(cr * 16 + r) * IMW + cc * 16 + c];
    }
    if (t < 48) {
        int s = t >> 2, kg = t & 3;
        int k0 = 32 * s + 8 * kg;
        unsigned v;
        if (k0 >= 360) v = 0x80000000u;
        else {
            int wi = k0 / 40, ci0 = k0 - wi * 40;
            int dr = wi / 3, dc = wi - 3 * dr;
            v = (unsigned)((dr * 17 + dc) * XS + ci0);
        }
        koff_s[t] = v;
    }
    __syncthreads();

    // ---- Phase B: conv1 + LN1 + gelu -> x1h (f16), plus zero border + constants ----
    {
        // zero-pad border positions (row 16, col 16)
        if (t >= 128 && t < 161) {
            int idx = t - 128;
            int pos2 = (idx < 17) ? (16 * 17 + idx) : ((idx - 17) * 17 + 16);
            v8h z = (v8h)0;
            #pragma unroll
            for (int chk = 0; chk < 5; chk++)
                *(v8h*)&x1h[pos2 * XS + chk * 8] = z;
        }
        int r = t >> 4, c = t & 15;
        int pos2 = r * 17 + c;
        if (r < 8 && c < 8) {
            float vin[9];
            #pragma unroll
            for (int dr = 0; dr < 3; dr++)
                #pragma unroll
                for (int dc = 0; dc < 3; dc++) {
                    int rr = 2 * r + dr, ccc = 2 * c + dc;
                    vin[dr * 3 + dc] = (rr < 16 && ccc < 16) ? img_s[rr][ccc] : 0.0f;
                }
            float y[CH];
            float mu = 0.f;
            for (int ch = 0; ch < CH; ch++) {
                float a = b1[ch];
                #pragma unroll
                for (int k = 0; k < 9; k++) a += vin[k] * w1[k * CH + ch];
                y[ch] = a; mu += a;
            }
            mu /= CH;
            float var = 0.f;
            for (int ch = 0; ch < CH; ch++) { float d = y[ch] - mu; var += d * d; }
            float rs = rsqrtf(var / CH + 1e-6f);
            #pragma unroll
            for (int chk = 0; chk < 5; chk++) {
                v8h hv;
                #pragma unroll
                for (int j = 0; j < 8; j++) {
                    int ch = chk * 8 + j;
                    float g = gelu_tanh((y[ch] - mu) * rs * s1[ch] + bb1[ch]);
                    hv[j] = (_Float16)g;
                }
                *(v8h*)&x1h[pos2 * XS + chk * 8] = hv;
            }
        } else {
            const v8h* zsrc = (const v8h*)&ws[Z1_OFF];
            #pragma unroll
            for (int chk = 0; chk < 5; chk++)
                *(v8h*)&x1h[pos2 * XS + chk * 8] = zsrc[chk];
        }
    }
    __syncthreads();

    // ---- Phase C: conv2 as MFMA f16 GEMM: [16 pos x 384k] @ [384k x 48co] per wave ----
    {
        const int wv   = t >> 6;
        const int lane = t & 63;
        const int row  = lane & 15;       // M index within tile
        const int kg   = lane >> 4;       // K group
        const int o    = (wv << 4) | row; // output position 0..63
        const int p = o >> 3, q = o & 7;
        const unsigned pbase = (unsigned)((34 * p + 2 * q) * XS);

        v4f acc0 = {0,0,0,0}, acc1 = {0,0,0,0}, acc2 = {0,0,0,0};
        const v8h* wtab = (const v8h*)ws;   // element (kgg*48 + co)

        #pragma unroll
        for (int s = 0; s < 12; s++) {
            unsigned koff = koff_s[(s << 2) | kg];
            unsigned aoff = (koff & 0x80000000u) ? 0u : (pbase + koff);
            v8h a = *(const v8h*)&x1h[aoff];
            const v8h* wb = wtab + ((s * 4 + kg) * 48);
            v8h bf0 = wb[row];
            v8h bf1 = wb[16 + row];
            v8h bf2 = wb[32 + row];
            acc0 = __builtin_amdgcn_mfma_f32_16x16x32_f16(a, bf0, acc0, 0, 0, 0);
            acc1 = __builtin_amdgcn_mfma_f32_16x16x32_f16(a, bf1, acc1, 0, 0, 0);
            acc2 = __builtin_amdgcn_mfma_f32_16x16x32_f16(a, bf2, acc2, 0, 0, 0);
        }

        // D layout: col = lane&15, row = (lane>>4)*4 + j
        const int co_b = lane & 15;
        float bb0 = b2g[co_b];
        float bb1e = b2g[16 + co_b];
        float bb2e = (co_b < 8) ? b2g[32 + co_b] : 0.f;
        #pragma unroll
        for (int j = 0; j < 4; j++) {
            int oo = (wv << 4) | (kg << 2) | j;
            y2s[oo * 41 + co_b]      = acc0[j] + bb0;
            y2s[oo * 41 + 16 + co_b] = acc1[j] + bb1e;
            if (co_b < 8)
                y2s[oo * 41 + 32 + co_b] = acc2[j] + bb2e;
        }
    }
    __syncthreads();

    // ---- Phase D: LN2 + gelu in place ----
    if (t < 64) {
        float mu = 0.f;
        for (int ch = 0; ch < CH; ch++) mu += y2s[t * 41 + ch];
        mu /= CH;
        float var = 0.f;
        for (int ch = 0; ch < CH; ch++) { float d = y2s[t * 41 + ch] - mu; var += d * d; }
        float rs = rsqrtf(var / CH + 1e-6f);
        for (int ch = 0; ch < CH; ch++) {
            float v = y2s[t * 41 + ch];
            y2s[t * 41 + ch] = gelu_tanh((v - mu) * rs * s2[ch] + bb2[ch]);
        }
    }
    __syncthreads();

    // ---- Phase E: dense [2560] @ [2560,6] ----
    {
        float acc[6] = {0.f, 0.f, 0.f, 0.f, 0.f, 0.f};
        int i0 = t * 10;
        for (int ii = 0; ii < 10; ii++) {
            int i = i0 + ii;
            int pos = i / CH, ch = i - pos * CH;
            float v = y2s[pos * 41 + ch];
            const float* wp = &dw[i * 6];
            #pragma unroll
            for (int k = 0; k < 6; k++) acc[k] += v * wp[k];
        }
        #pragma unroll
        for (int off = 32; off > 0; off >>= 1)
            #pragma unroll
            for (int k = 0; k < 6; k++) acc[k] += __shfl_down(acc[k], off, 64);
        int wv = t >> 6, lane = t & 63;
        if (lane == 0) {
            #pragma unroll
            for (int k = 0; k < 6; k++) red[wv][k] = acc[k];
        }
        __syncthreads();
        if (t == 0) {
            #pragma unroll
            for (int k = 0; k < 6; k++)
                out[f * 6 + k] = red[0][k] + red[1][k] + red[2][k] + red[3][k] + db[k];
        }
    }
}

extern "C" void kernel_launch(void* const* d_in, const int* in_sizes, int n_in,
                              void* d_out, int out_size, void* d_ws, size_t ws_size,
                              hipStream_t stream) {
    const float* img = (const float*)d_in[0];
    // d_in[1] = masks: analytically redundant (mask == cell id), not read.
    const float* w1  = (const float*)d_in[2];
    const float* b1  = (const float*)d_in[3];
    const float* s1  = (const float*)d_in[4];
    const float* bb1 = (const float*)d_in[5];
    const float* w2  = (const float*)d_in[6];
    const float* b2  = (const float*)d_in[7];
    const float* s2  = (const float*)d_in[8];
    const float* bb2 = (const float*)d_in[9];
    const float* dw  = (const float*)d_in[10];
    const float* db  = (const float*)d_in[11];
    float* out = (float*)d_out;
    _Float16* ws = (_Float16*)d_ws;

    prep_kernel<<<1, 256, 0, stream>>>(w2, b1, s1, bb1, ws);
    sgn_kernel<<<4096, 256, 0, stream>>>(img, w1, b1, s1, bb1,
                                         b2, s2, bb2, dw, db, ws, out);
}

// Round 3
// 62.129 us; speedup vs baseline: 12.8068x; 1.8152x over previous
//
#include <hip/hip_runtime.h>
#include <math.h>

#define CH 40
#define IMW 1024
#define XS 48                 // halves per x1 position (padded from 40)
#define W2T_HALVES (48*48*8)  // [kchunk 0..47][co 0..47][j 0..7]
#define Z1_OFF W2T_HALVES     // z1[40] halves right after w2t

typedef _Float16 v8h __attribute__((ext_vector_type(8)));
typedef _Float16 v4h __attribute__((ext_vector_type(4)));
typedef float    v4f __attribute__((ext_vector_type(4)));

// gelu(tanh approx) == x * sigmoid(2*0.79788456*(x+0.044715x^3)); ~6 fast insts
__device__ __forceinline__ float gelu_fast(float x) {
    float u = 1.5957691216057308f * (x + 0.044715f * x * x * x);
    return x * __builtin_amdgcn_rcpf(1.0f + __expf(-u));
}

// ---------------- pre-kernel: build f16 weight table + z1 in ws ----------------
__global__ __launch_bounds__(256) void prep_kernel(
    const float* __restrict__ w2,
    const float* __restrict__ b1, const float* __restrict__ s1,
    const float* __restrict__ bb1,
    _Float16* __restrict__ ws)
{
    int idx0 = blockIdx.x * 256 + threadIdx.x;
    for (int idx = idx0; idx < W2T_HALVES; idx += gridDim.x * 256) {
        int j   = idx & 7;
        int co  = (idx >> 3) % 48;
        int kgg = idx / (48 * 8);
        int k   = kgg * 8 + j;          // k = window*40 + ci
        float v = 0.0f;
        if (co < CH && k < 360) {
            int wi = k / 40, ci = k - wi * 40;
            v = w2[(wi * CH + ci) * CH + co];
        }
        ws[idx] = (_Float16)v;
    }
    if (blockIdx.x == 0 && threadIdx.x < CH) {
        int t = threadIdx.x;
        float mu = 0.f, m2 = 0.f;
        for (int i = 0; i < CH; i++) mu += b1[i];
        mu /= CH;
        for (int i = 0; i < CH; i++) { float d = b1[i] - mu; m2 += d * d; }
        float rs = rsqrtf(m2 / CH + 1e-6f);
        float y = (b1[t] - mu) * rs * s1[t] + bb1[t];
        ws[Z1_OFF + t] = (_Float16)gelu_fast(y);
    }
}

// ---------------- main kernel: one token per block ----------------
__global__ __launch_bounds__(256) void sgn_kernel(
    const float* __restrict__ img,
    const float* __restrict__ w1, const float* __restrict__ b1,
    const float* __restrict__ s1, const float* __restrict__ bb1,
    const float* __restrict__ b2g,
    const float* __restrict__ s2, const float* __restrict__ bb2,
    const float* __restrict__ dw, const float* __restrict__ db,
    const _Float16* __restrict__ ws,
    float* __restrict__ out)
{
    // x1h [17*17*XS] f16 (27744 B), later reused as y2f [64*41] f32 (10496 B)
    __shared__ __align__(16) unsigned char sbuf[17 * 17 * XS * 2];
    _Float16* x1h = (_Float16*)sbuf;
    float*    y2f = (float*)sbuf;
    __shared__ float img_s[16][16];
    __shared__ unsigned koff_s[48];
    __shared__ float red[4][6];

    const int f   = blockIdx.x;
    const int cfg = f >> 10;
    const int ij  = f & 1023;
    const int ti  = ij >> 5, tj = ij & 31;
    const int sx  = cfg & 1, sy = cfg >> 1;
    const int cr  = 2 * ti + sx, cc = 2 * tj + sy;

    const int t = threadIdx.x;

    // ---- Phase A: stage image cell + koff LUT ----
    {
        int r = t >> 4, c = t & 15;
        img_s[r][c] = img[(cr * 16 + r) * IMW + cc * 16 + c];
    }
    if (t < 48) {
        int s = t >> 2, kg = t & 3;
        int k0 = 32 * s + 8 * kg;
        unsigned v;
        if (k0 >= 360) v = 0x80000000u;
        else {
            int wi = k0 / 40, ci0 = k0 - wi * 40;
            int dr = wi / 3, dc = wi - 3 * dr;
            v = (unsigned)((dr * 17 + dc) * XS + ci0);
        }
        koff_s[t] = v;
    }
    __syncthreads();

    // ---- Phase B: conv1 + LN1 + gelu -> x1h (f16) ----
    if (t < 128) {
        // waves 0-1: 2 threads per output position, 20 channels each
        const int pos  = t >> 1;
        const int half = t & 1;
        const int r = pos >> 3, c = pos & 7;
        float vin[9];
        #pragma unroll
        for (int dr = 0; dr < 3; dr++)
            #pragma unroll
            for (int dc = 0; dc < 3; dc++) {
                int rr = 2 * r + dr, ccc = 2 * c + dc;
                vin[dr * 3 + dc] = (rr < 16 && ccc < 16) ? img_s[rr][ccc] : 0.0f;
            }
        const int ch0 = half * 20;
        float y[20];
        float s_own = 0.f;
        #pragma unroll
        for (int u = 0; u < 20; u++) {
            int ch = ch0 + u;
            float a = b1[ch];
            #pragma unroll
            for (int k = 0; k < 9; k++) a += vin[k] * w1[k * CH + ch];
            y[u] = a; s_own += a;
        }
        float mu = (s_own + __shfl_xor(s_own, 1, 64)) * (1.0f / CH);
        float v_own = 0.f;
        #pragma unroll
        for (int u = 0; u < 20; u++) { float d = y[u] - mu; v_own += d * d; }
        float var = (v_own + __shfl_xor(v_own, 1, 64)) * (1.0f / CH);
        float rs = rsqrtf(var + 1e-6f);
        _Float16 g[20];
        #pragma unroll
        for (int u = 0; u < 20; u++) {
            int ch = ch0 + u;
            g[u] = (_Float16)gelu_fast((y[u] - mu) * rs * s1[ch] + bb1[ch]);
        }
        const int base = (r * 17 + c) * XS + ch0;   // halves
        if (half == 0) {
            *(v8h*)&x1h[base]      = *(v8h*)&g[0];
            *(v8h*)&x1h[base + 8]  = *(v8h*)&g[8];
            *(v4h*)&x1h[base + 16] = *(v4h*)&g[16];
        } else {
            *(v4h*)&x1h[base]      = *(v4h*)&g[0];   // byte offset 40 within pos: 8-aligned
            *(v8h*)&x1h[base + 4]  = *(v8h*)&g[4];
            *(v8h*)&x1h[base + 12] = *(v8h*)&g[12];
        }
    } else {
        // waves 2-3: fill remaining 225 positions (z1 constant or zero border)
        v8h z0 = ((const v8h*)&ws[Z1_OFF])[0];
        v8h z1v = ((const v8h*)&ws[Z1_OFF])[1];
        v8h z2 = ((const v8h*)&ws[Z1_OFF])[2];
        v8h z3 = ((const v8h*)&ws[Z1_OFF])[3];
        v8h z4 = ((const v8h*)&ws[Z1_OFF])[4];
        v8h zz = (v8h)0;
        for (int pp = t - 128; pp < 289; pp += 128) {
            int r = pp / 17, c = pp - r * 17;
            if (r < 8 && c < 8) continue;
            bool zero = (r == 16) || (c == 16);
            int base = pp * XS;
            *(v8h*)&x1h[base]      = zero ? zz : z0;
            *(v8h*)&x1h[base + 8]  = zero ? zz : z1v;
            *(v8h*)&x1h[base + 16] = zero ? zz : z2;
            *(v8h*)&x1h[base + 24] = zero ? zz : z3;
            *(v8h*)&x1h[base + 32] = zero ? zz : z4;
        }
    }
    __syncthreads();

    // ---- Phase C: conv2 MFMA GEMM + fused LN2 + gelu (in-register) ----
    float g0[4], g1[4], g2[4];
    {
        const int wv   = t >> 6;
        const int lane = t & 63;
        const int row  = lane & 15;       // A-fragment M index
        const int kg   = lane >> 4;       // K group
        const int o    = (wv << 4) | row;
        const int p = o >> 3, q = o & 7;
        const unsigned pbase = (unsigned)((34 * p + 2 * q) * XS);

        v4f acc0 = {0,0,0,0}, acc1 = {0,0,0,0}, acc2 = {0,0,0,0};
        const v8h* wtab = (const v8h*)ws;

        #pragma unroll
        for (int s = 0; s < 12; s++) {
            unsigned koff = koff_s[(s << 2) | kg];
            unsigned aoff = (koff & 0x80000000u) ? 0u : (pbase + koff);
            v8h a = *(const v8h*)&x1h[aoff];
            const v8h* wb = wtab + ((s * 4 + kg) * 48);
            v8h bf0 = wb[row];
            v8h bf1 = wb[16 + row];
            v8h bf2 = wb[32 + row];
            acc0 = __builtin_amdgcn_mfma_f32_16x16x32_f16(a, bf0, acc0, 0, 0, 0);
            acc1 = __builtin_amdgcn_mfma_f32_16x16x32_f16(a, bf1, acc1, 0, 0, 0);
            acc2 = __builtin_amdgcn_mfma_f32_16x16x32_f16(a, bf2, acc2, 0, 0, 0);
        }

        // D layout: channel = lane&15 (+16/+32), position oo = (wv<<4)|(kg<<2)|j
        const int co_b = lane & 15;
        const bool has2 = (co_b < 8);
        const float bia0 = b2g[co_b];
        const float bia1 = b2g[16 + co_b];
        const float bia2 = has2 ? b2g[32 + co_b] : 0.f;
        const float sc0 = s2[co_b],        sb0 = bb2[co_b];
        const float sc1 = s2[16 + co_b],   sb1 = bb2[16 + co_b];
        const float sc2 = has2 ? s2[32 + co_b] : 0.f;
        const float sb2 = has2 ? bb2[32 + co_b] : 0.f;
        #pragma unroll
        for (int j = 0; j < 4; j++) {
            float v0 = acc0[j] + bia0;
            float v1 = acc1[j] + bia1;
            float v2 = has2 ? (acc2[j] + bia2) : 0.f;
            float s = v0 + v1 + v2;
            #pragma unroll
            for (int m = 1; m < 16; m <<= 1) s += __shfl_xor(s, m, 64);
            float mu = s * (1.0f / CH);
            float d0 = v0 - mu, d1 = v1 - mu, d2 = v2 - mu;
            float vv = d0 * d0 + d1 * d1 + (has2 ? d2 * d2 : 0.f);
            #pragma unroll
            for (int m = 1; m < 16; m <<= 1) vv += __shfl_xor(vv, m, 64);
            float rs = rsqrtf(vv * (1.0f / CH) + 1e-6f);
            g0[j] = gelu_fast(d0 * rs * sc0 + sb0);
            g1[j] = gelu_fast(d1 * rs * sc1 + sb1);
            g2[j] = has2 ? gelu_fast(d2 * rs * sc2 + sb2) : 0.f;
        }
    }
    __syncthreads();   // all x1h reads done; safe to overwrite with y2f

    {
        const int wv   = t >> 6;
        const int lane = t & 63;
        const int co_b = lane & 15;
        const int kg   = lane >> 4;
        #pragma unroll
        for (int j = 0; j < 4; j++) {
            int oo = (wv << 4) | (kg << 2) | j;
            y2f[oo * 41 + co_b]      = g0[j];
            y2f[oo * 41 + 16 + co_b] = g1[j];
            if (co_b < 8)
                y2f[oo * 41 + 32 + co_b] = g2[j];
        }
    }
    __syncthreads();

    // ---- Phase E: dense [2560] @ [2560,6] ----
    {
        float acc[6] = {0.f, 0.f, 0.f, 0.f, 0.f, 0.f};
        const int pos = t >> 2, ch0 = (t & 3) * 10;
        const float* wp0 = &dw[(t * 10) * 6];
        #pragma unroll
        for (int ii = 0; ii < 10; ii++) {
            float v = y2f[pos * 41 + ch0 + ii];
            const float* wp = wp0 + ii * 6;
            #pragma unroll
            for (int k = 0; k < 6; k++) acc[k] += v * wp[k];
        }
        #pragma unroll
        for (int off = 32; off > 0; off >>= 1)
            #pragma unroll
            for (int k = 0; k < 6; k++) acc[k] += __shfl_down(acc[k], off, 64);
        int wv = t >> 6, lane = t & 63;
        if (lane == 0) {
            #pragma unroll
            for (int k = 0; k < 6; k++) red[wv][k] = acc[k];
        }
        __syncthreads();
        if (t == 0) {
            #pragma unroll
            for (int k = 0; k < 6; k++)
                out[f * 6 + k] = red[0][k] + red[1][k] + red[2][k] + red[3][k] + db[k];
        }
    }
}

extern "C" void kernel_launch(void* const* d_in, const int* in_sizes, int n_in,
                              void* d_out, int out_size, void* d_ws, size_t ws_size,
                              hipStream_t stream) {
    const float* img = (const float*)d_in[0];
    // d_in[1] = masks: analytically redundant (mask == cell id), not read.
    const float* w1  = (const float*)d_in[2];
    const float* b1  = (const float*)d_in[3];
    const float* s1  = (const float*)d_in[4];
    const float* bb1 = (const float*)d_in[5];
    const float* w2  = (const float*)d_in[6];
    const float* b2  = (const float*)d_in[7];
    const float* s2  = (const float*)d_in[8];
    const float* bb2 = (const float*)d_in[9];
    const float* dw  = (const float*)d_in[10];
    const float* db  = (const float*)d_in[11];
    float* out = (float*)d_out;
    _Float16* ws = (_Float16*)d_ws;

    prep_kernel<<<32, 256, 0, stream>>>(w2, b1, s1, bb1, ws);
    sgn_kernel<<<4096, 256, 0, stream>>>(img, w1, b1, s1, bb1,
                                         b2, s2, bb2, dw, db, ws, out);
}